// Round 8
// baseline (132.954 us; speedup 1.0000x reference)
//
#include <hip/hip_runtime.h>
#include <math.h>

constexpr int kD   = 128;
constexpr int kE   = 256;
constexpr int kTok = 2048;

// ---------------- K1: gate (logits -> softmax -> top2) + zero done ----------
__global__ __launch_bounds__(256) void k_gate(
    const float* __restrict__ x, const float* __restrict__ gate_w,
    const float* __restrict__ gate_b,
    float2* __restrict__ tokinfo, int* __restrict__ top2,
    int* __restrict__ done)
{
    const int b  = blockIdx.x;
    const int t  = threadIdx.x;
    const int wv = t >> 6, ln = t & 63;

    if (t < 4) done[b * 4 + t] = 0;   // re-armed every launch (node boundary flushes)

    __shared__ float xsT[kD][4];
    __shared__ float partf[4][4];
    __shared__ int   parti[4][4];
    __shared__ int   pi0s[4];
    __shared__ float pv0s[4];

    {
        const float2 v = *(const float2*)(x + ((size_t)(b * 4 + wv)) * kD + ln * 2);
        xsT[ln * 2 + 0][wv] = v.x;
        xsT[ln * 2 + 1][wv] = v.y;
    }
    __syncthreads();

    float lg[4];
    {
        const float bias = gate_b[t];
        lg[0] = lg[1] = lg[2] = lg[3] = bias;
    }
    #pragma unroll 8
    for (int d = 0; d < kD; ++d) {
        const float w = gate_w[d * kE + t];
        const float4 xv = *(const float4*)&xsT[d][0];
        lg[0] = fmaf(xv.x, w, lg[0]);
        lg[1] = fmaf(xv.y, w, lg[1]);
        lg[2] = fmaf(xv.z, w, lg[2]);
        lg[3] = fmaf(xv.w, w, lg[3]);
    }

    // max
    float m[4];
    #pragma unroll
    for (int j = 0; j < 4; ++j) m[j] = lg[j];
    #pragma unroll
    for (int s = 1; s < 64; s <<= 1) {
        #pragma unroll
        for (int j = 0; j < 4; ++j) m[j] = fmaxf(m[j], __shfl_xor(m[j], s));
    }
    if (ln == 0) {
        #pragma unroll
        for (int j = 0; j < 4; ++j) partf[wv][j] = m[j];
    }
    __syncthreads();
    float mx[4];
    #pragma unroll
    for (int j = 0; j < 4; ++j)
        mx[j] = fmaxf(fmaxf(partf[0][j], partf[1][j]), fmaxf(partf[2][j], partf[3][j]));
    __syncthreads();

    // sum of exp
    float ex[4], sm[4];
    #pragma unroll
    for (int j = 0; j < 4; ++j) { ex[j] = __expf(lg[j] - mx[j]); sm[j] = ex[j]; }
    #pragma unroll
    for (int s = 1; s < 64; s <<= 1) {
        #pragma unroll
        for (int j = 0; j < 4; ++j) sm[j] += __shfl_xor(sm[j], s);
    }
    if (ln == 0) {
        #pragma unroll
        for (int j = 0; j < 4; ++j) partf[wv][j] = sm[j];
    }
    __syncthreads();
    float p[4];
    #pragma unroll
    for (int j = 0; j < 4; ++j) {
        const float tot = partf[0][j] + partf[1][j] + partf[2][j] + partf[3][j];
        p[j] = ex[j] / tot;
    }
    __syncthreads();

    // argmax pass 1 (ties -> lower index)
    float v[4]; int ix[4];
    #pragma unroll
    for (int j = 0; j < 4; ++j) { v[j] = p[j]; ix[j] = t; }
    #pragma unroll
    for (int s = 1; s < 64; s <<= 1) {
        #pragma unroll
        for (int j = 0; j < 4; ++j) {
            const float ov = __shfl_xor(v[j], s);
            const int   oi = __shfl_xor(ix[j], s);
            if (ov > v[j] || (ov == v[j] && oi < ix[j])) { v[j] = ov; ix[j] = oi; }
        }
    }
    if (ln == 0) {
        #pragma unroll
        for (int j = 0; j < 4; ++j) { partf[wv][j] = v[j]; parti[wv][j] = ix[j]; }
    }
    __syncthreads();
    if (t < 4) {
        const int j = t;
        float bv = partf[0][j]; int bi = parti[0][j];
        #pragma unroll
        for (int w = 1; w < 4; ++w) {
            const float ov = partf[w][j]; const int oi = parti[w][j];
            if (ov > bv || (ov == bv && oi < bi)) { bv = ov; bi = oi; }
        }
        pv0s[j] = bv; pi0s[j] = bi;
    }
    __syncthreads();

    // argmax pass 2 (mask winner)
    #pragma unroll
    for (int j = 0; j < 4; ++j) {
        v[j] = (t == pi0s[j]) ? -INFINITY : p[j];
        ix[j] = t;
    }
    #pragma unroll
    for (int s = 1; s < 64; s <<= 1) {
        #pragma unroll
        for (int j = 0; j < 4; ++j) {
            const float ov = __shfl_xor(v[j], s);
            const int   oi = __shfl_xor(ix[j], s);
            if (ov > v[j] || (ov == v[j] && oi < ix[j])) { v[j] = ov; ix[j] = oi; }
        }
    }
    if (ln == 0) {
        #pragma unroll
        for (int j = 0; j < 4; ++j) { partf[wv][j] = v[j]; parti[wv][j] = ix[j]; }
    }
    __syncthreads();
    if (t < 4) {
        const int j = t;
        float bv = partf[0][j]; int bi = parti[0][j];
        #pragma unroll
        for (int w = 1; w < 4; ++w) {
            const float ov = partf[w][j]; const int oi = parti[w][j];
            if (ov > bv || (ov == bv && oi < bi)) { bv = ov; bi = oi; }
        }
        const int tok = b * 4 + j;
        const float v0 = pv0s[j], v1 = bv;
        const float den = v0 + v1 + 1e-6f;
        tokinfo[tok] = make_float2(v0 / den, v1 / den);
        top2[tok] = pi0s[j] | (bi << 8);
    }
}

// ---------------- K2: expert matvecs + atomic-tail SwiGLU -------------------
// 512 blocks = (expert e, half hf) x 1024 thr. Pieces stored agent-scope
// (write-through to MALL). Per-entry done[tok] fetch_add; the 4th arriver
// computes that token's SwiGLU + consensus inline. No spins, no grid sync.
__global__ __launch_bounds__(1024) void k_expert_tail(
    const float* __restrict__ x, const float* __restrict__ expert_w,
    const int* __restrict__ top2, const float2* __restrict__ tokinfo,
    const float* __restrict__ w1m, const float* __restrict__ b1,
    const float* __restrict__ w2m, const float* __restrict__ b2,
    float* __restrict__ ybuf, int* __restrict__ done,
    float* __restrict__ out_avg, float* __restrict__ out_cons)
{
    const int e  = blockIdx.x >> 1;
    const int hf = blockIdx.x & 1;
    const int t  = threadIdx.x;

    __shared__ float W[kD][64];     // 32 KB
    __shared__ float xs[16][kD];    // 8 KB
    __shared__ int   llist[kTok];   // 8 KB
    __shared__ int   lcount;
    // tail
    __shared__ float  ysh[2][kD];
    __shared__ float  wav[kD];
    __shared__ float  part[2][4][kD];
    __shared__ float  red[kD];
    __shared__ int    nwin;
    __shared__ float2 tish;

    if (t == 0) { lcount = 0; nwin = 0; }
    __syncthreads();

    // build local token list (top2 is 8 KB, L2-hot)
    #pragma unroll
    for (int k = 0; k < 2; ++k) {
        const int i = k * 1024 + t;
        const int pk = top2[i];
        if ((pk & 255) == e)        llist[atomicAdd(&lcount, 1)] = i * 2;
        if (((pk >> 8) & 255) == e) llist[atomicAdd(&lcount, 1)] = i * 2 + 1;
    }

    // stage W half: W[r][c] = expert_w[e][r][hf*64+c]
    {
        const float* Wg = expert_w + (size_t)e * kD * kD + hf * 64;
        #pragma unroll
        for (int k = 0; k < 2; ++k) {
            const int f  = k * 1024 + t;
            const int r  = f >> 4;
            const int c4 = (f & 15) * 4;
            *(float4*)&W[r][c4] = *(const float4*)&Wg[(size_t)r * kD + c4];
        }
    }
    __syncthreads();
    const int n = lcount;

    const int Wv = t >> 6, ln = t & 63;
    for (int base = 0; base < n; base += 16) {
        const int m = min(16, n - base);
        for (int i = t; i < m * kD; i += 1024) {
            const int row = i >> 7, d = i & 127;
            const int ev = llist[base + row];
            xs[row][d] = x[(size_t)(ev >> 1) * kD + d];
        }
        __syncthreads();
        const int idx = base + Wv;
        if (idx < n) {
            float acc = 0.f;
            #pragma unroll 8
            for (int d = 0; d < kD; ++d)
                acc = fmaf(xs[Wv][d], W[d][ln], acc);   // xs: broadcast; W: 2-way (free)
            const int ev = llist[idx];
            // agent-scope write-through -> visible cross-XCD without L2 flush
            __hip_atomic_store(
                &ybuf[((size_t)(ev >> 1) * 2 + (ev & 1)) * kD + hf * 64 + ln],
                acc, __ATOMIC_RELAXED, __HIP_MEMORY_SCOPE_AGENT);
        }
        __syncthreads();   // drains vmcnt(0) for every wave before barrier
    }

    // read entry tokens BEFORE llist is reused for winners
    int mytok0 = -1, mytok1 = -1;
    if (t < n)        mytok0 = llist[t] >> 1;
    if (1024 + t < n) mytok1 = llist[1024 + t] >> 1;
    __syncthreads();

    if (mytok0 >= 0) {
        const int old = __hip_atomic_fetch_add(&done[mytok0], 1,
                          __ATOMIC_RELAXED, __HIP_MEMORY_SCOPE_AGENT);
        if (old == 3) llist[atomicAdd(&nwin, 1)] = mytok0;
    }
    if (mytok1 >= 0) {
        const int old = __hip_atomic_fetch_add(&done[mytok1], 1,
                          __ATOMIC_RELAXED, __HIP_MEMORY_SCOPE_AGENT);
        if (old == 3) llist[atomicAdd(&nwin, 1)] = mytok1;
    }
    __syncthreads();
    const int wn = nwin;

    // tail: SwiGLU + consensus for each won token (whole block per token)
    for (int wi = 0; wi < wn; ++wi) {
        const int tok = llist[wi];
        if (t < 256) {
            const float yv = __hip_atomic_load(&ybuf[(size_t)tok * 2 * kD + t],
                               __ATOMIC_RELAXED, __HIP_MEMORY_SCOPE_AGENT);
            ysh[t >> 7][t & 127] = yv;
        }
        if (t == 0) tish = tokinfo[tok];
        __syncthreads();
        if (t < kD) wav[t] = tish.x * ysh[0][t] + tish.y * ysh[1][t];
        __syncthreads();
        // matvec: t = h*512 + q*128 + o, 32 dims per thread
        {
            const int h = t >> 9, rem = t & 511, q = rem >> 7, o = rem & 127;
            const float* Wm = h ? w2m : w1m;
            const int d0 = q * 32;
            float acc = 0.f;
            #pragma unroll 8
            for (int dd = 0; dd < 32; ++dd)
                acc = fmaf(wav[d0 + dd], Wm[(size_t)(d0 + dd) * kD + o], acc);
            part[h][q][o] = acc;
        }
        __syncthreads();
        if (t < 256) {
            const int h = t >> 7, o = t & 127;
            const float s = part[h][0][o] + part[h][1][o] + part[h][2][o] + part[h][3][o]
                            + (h ? b2[o] : b1[o]);
            part[h][0][o] = s;
        }
        __syncthreads();
        if (t < kD) {
            const float g   = part[0][0][t];
            const float vvv = part[1][0][t];
            const float r = g * (1.f / (1.f + __expf(-g))) * vvv;
            out_avg[(size_t)tok * kD + t] = r;
            const float dd0 = ysh[0][t] - r, dd1 = ysh[1][t] - r;
            red[t] = tish.x * dd0 * dd0 + tish.y * dd1 * dd1;
        }
        __syncthreads();
        if (t < 64) {
            float s = red[t] + red[t + 64];
            #pragma unroll
            for (int sft = 1; sft < 64; sft <<= 1) s += __shfl_xor(s, sft);
            if (t == 0) out_cons[tok] = __expf(-s * (1.0f / (float)kD));
        }
        __syncthreads();
    }
}

extern "C" void kernel_launch(void* const* d_in, const int* in_sizes, int n_in,
                              void* d_out, int out_size, void* d_ws, size_t ws_size,
                              hipStream_t stream) {
    const float*  x        = (const float*)d_in[0];
    const float*  gate_w   = (const float*)d_in[1];
    const float*  gate_b   = (const float*)d_in[2];
    const float*  expert_w = (const float*)d_in[3];
    const float*  w1m      = (const float*)d_in[4];
    const float*  b1       = (const float*)d_in[5];
    const float*  w2m      = (const float*)d_in[6];
    const float*  b2       = (const float*)d_in[7];

    float* out_avg  = (float*)d_out;
    float* out_cons = out_avg + (size_t)kTok * kD;

    char*   ws      = (char*)d_ws;
    float2* tokinfo = (float2*)ws;                 // 16 KB
    int*    top2    = (int*)(ws + 16384);          // 8 KB
    int*    done    = (int*)(ws + 24576);          // 8 KB
    float*  ybuf    = (float*)(ws + 32768);        // 2 MB

    k_gate<<<kTok / 4, 256, 0, stream>>>(x, gate_w, gate_b, tokinfo, top2, done);
    k_expert_tail<<<kE * 2, 1024, 0, stream>>>(x, expert_w, top2, tokinfo,
                                               w1m, b1, w2m, b2,
                                               ybuf, done, out_avg, out_cons);
}

// Round 9
// 49.071 us; speedup vs baseline: 2.7094x; 2.7094x over previous
//
#include <hip/hip_runtime.h>
#include <math.h>

constexpr int kD   = 128;
constexpr int kE   = 256;
constexpr int kTok = 2048;

// ---------------- K1: gate (logits -> fused top2 -> softmax weights) --------
// 512 blocks x 256 threads; block handles 4 tokens; thread t = expert t.
// Single butterfly maintains (m1,i1,m2,i2); top-2 of softmax == top-2 of
// logits, v0 = 1/tot, v1 = exp(m2-m1)/tot.
__global__ __launch_bounds__(256) void k_gate(
    const float* __restrict__ x, const float* __restrict__ gate_w,
    const float* __restrict__ gate_b,
    float2* __restrict__ tokinfo, int* __restrict__ top2)
{
    const int b  = blockIdx.x;
    const int t  = threadIdx.x;
    const int wv = t >> 6, ln = t & 63;

    __shared__ float xsT[kD][4];
    __shared__ float pm1[4][4], pm2[4][4];   // [wave][token]
    __shared__ int   pi1[4][4], pi2[4][4];
    __shared__ float psum[4][4];

    {
        const float2 v = *(const float2*)(x + ((size_t)(b * 4 + wv)) * kD + ln * 2);
        xsT[ln * 2 + 0][wv] = v.x;
        xsT[ln * 2 + 1][wv] = v.y;
    }
    __syncthreads();

    float lg[4];
    {
        const float bias = gate_b[t];
        lg[0] = lg[1] = lg[2] = lg[3] = bias;
    }
    #pragma unroll 8
    for (int d = 0; d < kD; ++d) {
        const float w = gate_w[d * kE + t];
        const float4 xv = *(const float4*)&xsT[d][0];
        lg[0] = fmaf(xv.x, w, lg[0]);
        lg[1] = fmaf(xv.y, w, lg[1]);
        lg[2] = fmaf(xv.z, w, lg[2]);
        lg[3] = fmaf(xv.w, w, lg[3]);
    }

    // ---- fused top-2 butterfly (values sorted desc, ties -> lower index) ---
    float m1[4], m2[4]; int i1[4], i2[4];
    #pragma unroll
    for (int j = 0; j < 4; ++j) {
        m1[j] = lg[j]; i1[j] = t;
        m2[j] = -INFINITY; i2[j] = 0x7fffffff;
    }
    #pragma unroll
    for (int s = 1; s < 64; s <<= 1) {
        #pragma unroll
        for (int j = 0; j < 4; ++j) {
            const float b1 = __shfl_xor(m1[j], s);
            const int   j1 = __shfl_xor(i1[j], s);
            const float b2 = __shfl_xor(m2[j], s);
            const int   j2 = __shfl_xor(i2[j], s);
            const bool bw = (b1 > m1[j]) || (b1 == m1[j] && j1 < i1[j]);
            const float t1  = bw ? b1 : m1[j];  const int ti1 = bw ? j1 : i1[j];
            const float o1  = bw ? m1[j] : b1;  const int oi1 = bw ? i1[j] : j1;
            const float w2  = bw ? b2 : m2[j];  const int wi2 = bw ? j2 : i2[j];
            const bool sw = (o1 > w2) || (o1 == w2 && oi1 < wi2);
            m1[j] = t1; i1[j] = ti1;
            m2[j] = sw ? o1 : w2; i2[j] = sw ? oi1 : wi2;
        }
    }
    if (ln == 0) {
        #pragma unroll
        for (int j = 0; j < 4; ++j) {
            pm1[wv][j] = m1[j]; pi1[wv][j] = i1[j];
            pm2[wv][j] = m2[j]; pi2[wv][j] = i2[j];
        }
    }
    __syncthreads();

    // finalizer merges 4 wave partials (thread j handles token j)
    __shared__ float gmx[4];
    if (t < 4) {
        const int j = t;
        float a1 = pm1[0][j], a2 = pm2[0][j];
        int   x1 = pi1[0][j], x2 = pi2[0][j];
        #pragma unroll
        for (int w = 1; w < 4; ++w) {
            const float b1 = pm1[w][j], b2 = pm2[w][j];
            const int   j1 = pi1[w][j], j2 = pi2[w][j];
            const bool bw = (b1 > a1) || (b1 == a1 && j1 < x1);
            const float t1  = bw ? b1 : a1;  const int ti1 = bw ? j1 : x1;
            const float o1  = bw ? a1 : b1;  const int oi1 = bw ? x1 : j1;
            const float w2  = bw ? b2 : a2;  const int wi2 = bw ? j2 : x2;
            const bool sw = (o1 > w2) || (o1 == w2 && oi1 < wi2);
            a1 = t1; x1 = ti1;
            a2 = sw ? o1 : w2; x2 = sw ? oi1 : wi2;
        }
        pm1[0][j] = a1; pi1[0][j] = x1;   // store merged top-2
        pm2[0][j] = a2; pi2[0][j] = x2;
        gmx[j] = a1;
    }
    __syncthreads();

    // ---- sum of exp (mx = global top-1 logit) ----
    float sm[4];
    #pragma unroll
    for (int j = 0; j < 4; ++j) sm[j] = __expf(lg[j] - gmx[j]);
    #pragma unroll
    for (int s = 1; s < 64; s <<= 1) {
        #pragma unroll
        for (int j = 0; j < 4; ++j) sm[j] += __shfl_xor(sm[j], s);
    }
    if (ln == 0) {
        #pragma unroll
        for (int j = 0; j < 4; ++j) psum[wv][j] = sm[j];
    }
    __syncthreads();

    if (t < 4) {
        const int j = t;
        const float tot = psum[0][j] + psum[1][j] + psum[2][j] + psum[3][j];
        const float v0 = 1.0f / tot;
        const float v1 = __expf(pm2[0][j] - pm1[0][j]) / tot;
        const float den = v0 + v1 + 1e-6f;
        const int tok = b * 4 + j;
        tokinfo[tok] = make_float2(v0 / den, v1 / den);
        top2[tok] = pi1[0][j] | (pi2[0][j] << 8);
    }
}

// ---------------- K2: expert-grouped matvecs --------------------------------
// 512 blocks = (hf = bid>>8, e = bid&255) x 1024 threads (16 waves).
// Both halves of expert e land on XCD e%8 (blockIdx round-robin) -> staging
// rows shared in one L2; across replays each XCD's 32 experts (2 MB) stay
// L2-resident.
__global__ __launch_bounds__(1024) void k_expert(
    const float* __restrict__ x, const float* __restrict__ expert_w,
    const int* __restrict__ top2, float* __restrict__ ybuf)
{
    const int e  = blockIdx.x & 255;
    const int hf = blockIdx.x >> 8;
    const int t  = threadIdx.x;

    __shared__ float W[kD][64];    // 32 KB, cols hf*64 .. hf*64+63
    __shared__ float xs[16][kD];   // 8 KB
    __shared__ int   llist[kTok];  // 8 KB
    __shared__ int   lcount;

    if (t == 0) lcount = 0;
    __syncthreads();

    #pragma unroll
    for (int k = 0; k < 2; ++k) {
        const int i = k * 1024 + t;
        const int pk = top2[i];
        if ((pk & 255) == e)        llist[atomicAdd(&lcount, 1)] = i * 2;
        if (((pk >> 8) & 255) == e) llist[atomicAdd(&lcount, 1)] = i * 2 + 1;
    }

    {
        const float* Wg = expert_w + (size_t)e * kD * kD + hf * 64;
        #pragma unroll
        for (int k = 0; k < 2; ++k) {
            const int f  = k * 1024 + t;
            const int r  = f >> 4;
            const int c4 = (f & 15) * 4;
            *(float4*)&W[r][c4] = *(const float4*)&Wg[(size_t)r * kD + c4];
        }
    }
    __syncthreads();
    const int n = lcount;

    const int Wv = t >> 6, ln = t & 63;
    for (int base = 0; base < n; base += 16) {
        const int m = min(16, n - base);
        for (int i = t; i < m * kD; i += 1024) {
            const int row = i >> 7, d = i & 127;
            const int ev = llist[base + row];
            xs[row][d] = x[(size_t)(ev >> 1) * kD + d];
        }
        __syncthreads();

        const int idx = base + Wv;
        if (idx < n) {
            float acc = 0.f;
            #pragma unroll 8
            for (int d = 0; d < kD; ++d)
                acc = fmaf(xs[Wv][d], W[d][ln], acc);   // xs: broadcast; W: 2-way (free)
            const int ev = llist[idx];
            ybuf[((size_t)(ev >> 1) * 2 + (ev & 1)) * kD + hf * 64 + ln] = acc;
        }
        __syncthreads();
    }
}

// ---------------- K3: combine + SwiGLU + consensus --------------------------
// 512 blocks x 256 threads; block handles 4 tokens.
__global__ __launch_bounds__(256) void k_swiglu(
    const float* __restrict__ ybuf, const float2* __restrict__ tokinfo,
    const float* __restrict__ w1m, const float* __restrict__ b1,
    const float* __restrict__ w2m, const float* __restrict__ b2,
    float* __restrict__ out_avg, float* __restrict__ out_cons)
{
    const int b = blockIdx.x;
    const int t = threadIdx.x;
    const int tok0 = b * 4;

    __shared__ float  ys[4 * 2 * kD];
    __shared__ float  wvT[kD][4];
    __shared__ float  vv[4][kD];
    __shared__ float  os[4][kD];
    __shared__ float2 ti[4];

    *(float4*)&ys[t * 4] = *(const float4*)&ybuf[(size_t)tok0 * 2 * kD + t * 4];
    if (t < 4) ti[t] = tokinfo[tok0 + t];
    __syncthreads();

    #pragma unroll
    for (int k = 0; k < 2; ++k) {
        const int idx = t * 2 + k;
        const int j = idx >> 7, o = idx & 127;
        const float2 w = ti[j];
        wvT[o][j] = w.x * ys[(j * 2 + 0) * kD + o] + w.y * ys[(j * 2 + 1) * kD + o];
    }
    __syncthreads();

    const int h = t >> 7, o = t & 127;
    const float* Wm = h ? w2m : w1m;
    const float bias = h ? b2[o] : b1[o];
    float a0 = bias, a1 = bias, a2 = bias, a3 = bias;
    #pragma unroll 4
    for (int d = 0; d < kD; ++d) {
        const float w = Wm[d * kD + o];
        const float4 xv = *(const float4*)&wvT[d][0];
        a0 = fmaf(xv.x, w, a0);
        a1 = fmaf(xv.y, w, a1);
        a2 = fmaf(xv.z, w, a2);
        a3 = fmaf(xv.w, w, a3);
    }
    if (h) { vv[0][o] = a0; vv[1][o] = a1; vv[2][o] = a2; vv[3][o] = a3; }
    __syncthreads();
    if (!h) {
        float gg[4] = {a0, a1, a2, a3};
        #pragma unroll
        for (int j = 0; j < 4; ++j) {
            const float g = gg[j];
            const float r = g * (1.f / (1.f + __expf(-g))) * vv[j][o];
            os[j][o] = r;
            out_avg[(size_t)(tok0 + j) * kD + o] = r;
        }
    }
    __syncthreads();

    const int wv = t >> 6, ln = t & 63;
    const float2 w = ti[wv];
    float s = 0.f;
    #pragma unroll
    for (int k = 0; k < 2; ++k) {
        const int oo = ln * 2 + k;
        const float ot = os[wv][oo];
        const float d0 = ys[(wv * 2 + 0) * kD + oo] - ot;
        const float d1 = ys[(wv * 2 + 1) * kD + oo] - ot;
        s += w.x * d0 * d0 + w.y * d1 * d1;
    }
    #pragma unroll
    for (int sft = 1; sft < 64; sft <<= 1) s += __shfl_xor(s, sft);
    if (ln == 0) out_cons[tok0 + wv] = __expf(-s * (1.0f / (float)kD));
}

extern "C" void kernel_launch(void* const* d_in, const int* in_sizes, int n_in,
                              void* d_out, int out_size, void* d_ws, size_t ws_size,
                              hipStream_t stream) {
    const float*  x        = (const float*)d_in[0];
    const float*  gate_w   = (const float*)d_in[1];
    const float*  gate_b   = (const float*)d_in[2];
    const float*  expert_w = (const float*)d_in[3];
    const float*  w1m      = (const float*)d_in[4];
    const float*  b1       = (const float*)d_in[5];
    const float*  w2m      = (const float*)d_in[6];
    const float*  b2       = (const float*)d_in[7];

    float* out_avg  = (float*)d_out;
    float* out_cons = out_avg + (size_t)kTok * kD;

    char*   ws      = (char*)d_ws;
    float2* tokinfo = (float2*)ws;                 // 16 KB
    int*    top2    = (int*)(ws + 16384);          // 8 KB
    float*  ybuf    = (float*)(ws + 32768);        // 2 MB

    k_gate  <<<kTok / 4, 256,  0, stream>>>(x, gate_w, gate_b, tokinfo, top2);
    k_expert<<<kE * 2,   1024, 0, stream>>>(x, expert_w, top2, ybuf);
    k_swiglu<<<kTok / 4, 256,  0, stream>>>(ybuf, tokinfo, w1m, b1, w2m, b2, out_avg, out_cons);
}

// Round 10
// 35.050 us; speedup vs baseline: 3.7932x; 1.4000x over previous
//
#include <hip/hip_runtime.h>
#include <math.h>

constexpr int kD   = 128;
constexpr int kE   = 256;
constexpr int kTok = 2048;

// ---------------- K1: gate (logits -> softmax -> top2) ----------------------
// R7-proven version, byte-identical.
__global__ __launch_bounds__(256) void k_gate(
    const float* __restrict__ x, const float* __restrict__ gate_w,
    const float* __restrict__ gate_b,
    float2* __restrict__ tokinfo, int* __restrict__ top2)
{
    const int b  = blockIdx.x;
    const int t  = threadIdx.x;
    const int wv = t >> 6, ln = t & 63;

    __shared__ float xsT[kD][4];
    __shared__ float partf[4][4];
    __shared__ int   parti[4][4];
    __shared__ int   pi0s[4];
    __shared__ float pv0s[4];

    {
        const float2 v = *(const float2*)(x + ((size_t)(b * 4 + wv)) * kD + ln * 2);
        xsT[ln * 2 + 0][wv] = v.x;
        xsT[ln * 2 + 1][wv] = v.y;
    }
    __syncthreads();

    float lg[4];
    {
        const float bias = gate_b[t];
        lg[0] = lg[1] = lg[2] = lg[3] = bias;
    }
    #pragma unroll 8
    for (int d = 0; d < kD; ++d) {
        const float w = gate_w[d * kE + t];
        const float4 xv = *(const float4*)&xsT[d][0];
        lg[0] = fmaf(xv.x, w, lg[0]);
        lg[1] = fmaf(xv.y, w, lg[1]);
        lg[2] = fmaf(xv.z, w, lg[2]);
        lg[3] = fmaf(xv.w, w, lg[3]);
    }

    // max over experts
    float m[4];
    #pragma unroll
    for (int j = 0; j < 4; ++j) m[j] = lg[j];
    #pragma unroll
    for (int s = 1; s < 64; s <<= 1) {
        #pragma unroll
        for (int j = 0; j < 4; ++j) m[j] = fmaxf(m[j], __shfl_xor(m[j], s));
    }
    if (ln == 0) {
        #pragma unroll
        for (int j = 0; j < 4; ++j) partf[wv][j] = m[j];
    }
    __syncthreads();
    float mx[4];
    #pragma unroll
    for (int j = 0; j < 4; ++j)
        mx[j] = fmaxf(fmaxf(partf[0][j], partf[1][j]), fmaxf(partf[2][j], partf[3][j]));
    __syncthreads();

    // sum of exp
    float ex[4], sm[4];
    #pragma unroll
    for (int j = 0; j < 4; ++j) { ex[j] = __expf(lg[j] - mx[j]); sm[j] = ex[j]; }
    #pragma unroll
    for (int s = 1; s < 64; s <<= 1) {
        #pragma unroll
        for (int j = 0; j < 4; ++j) sm[j] += __shfl_xor(sm[j], s);
    }
    if (ln == 0) {
        #pragma unroll
        for (int j = 0; j < 4; ++j) partf[wv][j] = sm[j];
    }
    __syncthreads();
    float p[4];
    #pragma unroll
    for (int j = 0; j < 4; ++j) {
        const float tot = partf[0][j] + partf[1][j] + partf[2][j] + partf[3][j];
        p[j] = ex[j] / tot;
    }
    __syncthreads();

    // argmax pass 1 (ties -> lower index)
    float v[4]; int ix[4];
    #pragma unroll
    for (int j = 0; j < 4; ++j) { v[j] = p[j]; ix[j] = t; }
    #pragma unroll
    for (int s = 1; s < 64; s <<= 1) {
        #pragma unroll
        for (int j = 0; j < 4; ++j) {
            const float ov = __shfl_xor(v[j], s);
            const int   oi = __shfl_xor(ix[j], s);
            if (ov > v[j] || (ov == v[j] && oi < ix[j])) { v[j] = ov; ix[j] = oi; }
        }
    }
    if (ln == 0) {
        #pragma unroll
        for (int j = 0; j < 4; ++j) { partf[wv][j] = v[j]; parti[wv][j] = ix[j]; }
    }
    __syncthreads();
    if (t < 4) {
        const int j = t;
        float bv = partf[0][j]; int bi = parti[0][j];
        #pragma unroll
        for (int w = 1; w < 4; ++w) {
            const float ov = partf[w][j]; const int oi = parti[w][j];
            if (ov > bv || (ov == bv && oi < bi)) { bv = ov; bi = oi; }
        }
        pv0s[j] = bv; pi0s[j] = bi;
    }
    __syncthreads();

    // argmax pass 2 (mask winner)
    #pragma unroll
    for (int j = 0; j < 4; ++j) {
        v[j] = (t == pi0s[j]) ? -INFINITY : p[j];
        ix[j] = t;
    }
    #pragma unroll
    for (int s = 1; s < 64; s <<= 1) {
        #pragma unroll
        for (int j = 0; j < 4; ++j) {
            const float ov = __shfl_xor(v[j], s);
            const int   oi = __shfl_xor(ix[j], s);
            if (ov > v[j] || (ov == v[j] && oi < ix[j])) { v[j] = ov; ix[j] = oi; }
        }
    }
    if (ln == 0) {
        #pragma unroll
        for (int j = 0; j < 4; ++j) { partf[wv][j] = v[j]; parti[wv][j] = ix[j]; }
    }
    __syncthreads();
    if (t < 4) {
        const int j = t;
        float bv = partf[0][j]; int bi = parti[0][j];
        #pragma unroll
        for (int w = 1; w < 4; ++w) {
            const float ov = partf[w][j]; const int oi = parti[w][j];
            if (ov > bv || (ov == bv && oi < bi)) { bv = ov; bi = oi; }
        }
        const int tok = b * 4 + j;
        const float v0 = pv0s[j], v1 = bv;
        const float den = v0 + v1 + 1e-6f;
        tokinfo[tok] = make_float2(v0 / den, v1 / den);
        top2[tok] = pi0s[j] | (bi << 8);
    }
}

// ---------------- K2: expert-grouped matvecs, 4-entry register-blocked ------
// 512 blocks = (expert e = bid>>1, half hf = bid&1) x 1024 threads (16 waves).
// Wave processes 4 entries with 4 accumulators: per d, 1 W read (2-way, free)
// + 4 xs broadcasts = 1.25 LDS instr/entry vs 2.0 before; 64 entries/round.
// LDS 72 KB -> 2 blocks/CU, 32 waves/CU.
__global__ __launch_bounds__(1024) void k_expert(
    const float* __restrict__ x, const float* __restrict__ expert_w,
    const int* __restrict__ top2, float* __restrict__ ybuf)
{
    const int e  = blockIdx.x >> 1;
    const int hf = blockIdx.x & 1;
    const int t  = threadIdx.x;

    __shared__ float W[kD][64];    // 32 KB
    __shared__ float xs[64][kD];   // 32 KB
    __shared__ int   llist[kTok];  // 8 KB
    __shared__ int   lcount;

    if (t == 0) lcount = 0;
    __syncthreads();

    // build local token list (top2 is 8 KB, L2-hot)
    #pragma unroll
    for (int k = 0; k < 2; ++k) {
        const int i = k * 1024 + t;
        const int pk = top2[i];
        if ((pk & 255) == e)        llist[atomicAdd(&lcount, 1)] = i * 2;
        if (((pk >> 8) & 255) == e) llist[atomicAdd(&lcount, 1)] = i * 2 + 1;
    }

    // stage W half: W[r][c] = expert_w[e][r][hf*64+c]
    {
        const float* Wg = expert_w + (size_t)e * kD * kD + hf * 64;
        #pragma unroll
        for (int k = 0; k < 2; ++k) {
            const int f  = k * 1024 + t;
            const int r  = f >> 4;
            const int c4 = (f & 15) * 4;
            *(float4*)&W[r][c4] = *(const float4*)&Wg[(size_t)r * kD + c4];
        }
    }
    __syncthreads();
    const int n = lcount;

    const int wv = t >> 6, ln = t & 63;
    for (int base = 0; base < n; base += 64) {
        const int m = min(64, n - base);
        // stage m x-rows (coalesced; stride-1 LDS writes = 2-way free)
        for (int i = t; i < m * kD; i += 1024) {
            const int row = i >> 7, d = i & 127;
            const int ev = llist[base + row];
            xs[row][d] = x[(size_t)(ev >> 1) * kD + d];
        }
        __syncthreads();

        const int i0 = base + wv * 4;       // wave's first entry (global idx)
        if (i0 < n) {
            const int r0 = wv * 4;          // row in xs
            const int cnt = min(4, n - i0);
            float a0 = 0.f, a1 = 0.f, a2 = 0.f, a3 = 0.f;
            #pragma unroll 8
            for (int d = 0; d < kD; ++d) {
                const float w = W[d][ln];   // 2-way bank alias: free
                a0 = fmaf(xs[r0 + 0][d], w, a0);   // broadcasts
                a1 = fmaf(xs[r0 + 1][d], w, a1);   // rows >= cnt: stale data,
                a2 = fmaf(xs[r0 + 2][d], w, a2);   // never stored
                a3 = fmaf(xs[r0 + 3][d], w, a3);
            }
            // explicitly unrolled guarded stores (no runtime-indexed reg array)
            {
                const int ev0 = llist[i0];
                ybuf[((size_t)(ev0 >> 1) * 2 + (ev0 & 1)) * kD + hf * 64 + ln] = a0;
            }
            if (cnt > 1) {
                const int ev1 = llist[i0 + 1];
                ybuf[((size_t)(ev1 >> 1) * 2 + (ev1 & 1)) * kD + hf * 64 + ln] = a1;
            }
            if (cnt > 2) {
                const int ev2 = llist[i0 + 2];
                ybuf[((size_t)(ev2 >> 1) * 2 + (ev2 & 1)) * kD + hf * 64 + ln] = a2;
            }
            if (cnt > 3) {
                const int ev3 = llist[i0 + 3];
                ybuf[((size_t)(ev3 >> 1) * 2 + (ev3 & 1)) * kD + hf * 64 + ln] = a3;
            }
        }
        __syncthreads();
    }
}

// ---------------- K3: combine + SwiGLU + consensus --------------------------
// R7-proven version, byte-identical.
__global__ __launch_bounds__(256) void k_swiglu(
    const float* __restrict__ ybuf, const float2* __restrict__ tokinfo,
    const float* __restrict__ w1m, const float* __restrict__ b1,
    const float* __restrict__ w2m, const float* __restrict__ b2,
    float* __restrict__ out_avg, float* __restrict__ out_cons)
{
    const int b = blockIdx.x;
    const int t = threadIdx.x;
    const int tok0 = b * 4;

    __shared__ float  ys[4 * 2 * kD];
    __shared__ float  wvT[kD][4];
    __shared__ float  vv[4][kD];
    __shared__ float  os[4][kD];
    __shared__ float2 ti[4];

    *(float4*)&ys[t * 4] = *(const float4*)&ybuf[(size_t)tok0 * 2 * kD + t * 4];
    if (t < 4) ti[t] = tokinfo[tok0 + t];
    __syncthreads();

    #pragma unroll
    for (int k = 0; k < 2; ++k) {
        const int idx = t * 2 + k;
        const int j = idx >> 7, o = idx & 127;
        const float2 w = ti[j];
        wvT[o][j] = w.x * ys[(j * 2 + 0) * kD + o] + w.y * ys[(j * 2 + 1) * kD + o];
    }
    __syncthreads();

    const int h = t >> 7, o = t & 127;
    const float* Wm = h ? w2m : w1m;
    const float bias = h ? b2[o] : b1[o];
    float a0 = bias, a1 = bias, a2 = bias, a3 = bias;
    #pragma unroll 4
    for (int d = 0; d < kD; ++d) {
        const float w = Wm[d * kD + o];
        const float4 xv = *(const float4*)&wvT[d][0];
        a0 = fmaf(xv.x, w, a0);
        a1 = fmaf(xv.y, w, a1);
        a2 = fmaf(xv.z, w, a2);
        a3 = fmaf(xv.w, w, a3);
    }
    if (h) { vv[0][o] = a0; vv[1][o] = a1; vv[2][o] = a2; vv[3][o] = a3; }
    __syncthreads();
    if (!h) {
        float gg[4] = {a0, a1, a2, a3};
        #pragma unroll
        for (int j = 0; j < 4; ++j) {
            const float g = gg[j];
            const float r = g * (1.f / (1.f + __expf(-g))) * vv[j][o];
            os[j][o] = r;
            out_avg[(size_t)(tok0 + j) * kD + o] = r;
        }
    }
    __syncthreads();

    const int wv = t >> 6, ln = t & 63;
    const float2 w = ti[wv];
    float s = 0.f;
    #pragma unroll
    for (int k = 0; k < 2; ++k) {
        const int oo = ln * 2 + k;
        const float ot = os[wv][oo];
        const float d0 = ys[(wv * 2 + 0) * kD + oo] - ot;
        const float d1 = ys[(wv * 2 + 1) * kD + oo] - ot;
        s += w.x * d0 * d0 + w.y * d1 * d1;
    }
    #pragma unroll
    for (int sft = 1; sft < 64; sft <<= 1) s += __shfl_xor(s, sft);
    if (ln == 0) out_cons[tok0 + wv] = __expf(-s * (1.0f / (float)kD));
}

extern "C" void kernel_launch(void* const* d_in, const int* in_sizes, int n_in,
                              void* d_out, int out_size, void* d_ws, size_t ws_size,
                              hipStream_t stream) {
    const float*  x        = (const float*)d_in[0];
    const float*  gate_w   = (const float*)d_in[1];
    const float*  gate_b   = (const float*)d_in[2];
    const float*  expert_w = (const float*)d_in[3];
    const float*  w1m      = (const float*)d_in[4];
    const float*  b1       = (const float*)d_in[5];
    const float*  w2m      = (const float*)d_in[6];
    const float*  b2       = (const float*)d_in[7];

    float* out_avg  = (float*)d_out;
    float* out_cons = out_avg + (size_t)kTok * kD;

    char*   ws      = (char*)d_ws;
    float2* tokinfo = (float2*)ws;                 // 16 KB
    int*    top2    = (int*)(ws + 16384);          // 8 KB
    float*  ybuf    = (float*)(ws + 32768);        // 2 MB

    k_gate  <<<kTok / 4, 256,  0, stream>>>(x, gate_w, gate_b, tokinfo, top2);
    k_expert<<<kE * 2,   1024, 0, stream>>>(x, expert_w, top2, ybuf);
    k_swiglu<<<kTok / 4, 256,  0, stream>>>(ybuf, tokinfo, w1m, b1, w2m, b2, out_avg, out_cons);
}